// Round 3
// baseline (430.519 us; speedup 1.0000x reference)
//
#include <hip/hip_runtime.h>
#include <stdint.h>

// ---------------------------------------------------------------------------
// GCN block: 3 x [ h = leaky_relu(in @ W);  out = (adj + I) @ h ]
// B=64, N=4096, D=16.  GEMM M=4096 x C=1024 x K=4096 bf16 MFMA, fp32 accum.
// Round 3: K-split-4 (grid 1024 -> 3-4 blocks/CU, m97-style inter-block
// overlap), single-buffer BK=64 tile 128x128, XOR-swizzled LDS, fp32
// unsafeAtomicAdd partial accumulation (ks-groups pinned to one XCD).
// Workspace: adjI bf16 32MB | hT bf16 8MB | ows fp32 16MB
// ---------------------------------------------------------------------------

typedef __bf16 bf16x8 __attribute__((ext_vector_type(8)));
typedef float  f32x4  __attribute__((ext_vector_type(4)));
typedef unsigned short ushort8 __attribute__((ext_vector_type(8)));

typedef __attribute__((address_space(1))) void* as1p;
typedef __attribute__((address_space(3))) void* as3p;
#define GLOAD_LDS16(G, L) \
  __builtin_amdgcn_global_load_lds((as1p)(G), (as3p)(L), 16, 0, 0)

__device__ __forceinline__ unsigned short f2bf(float f) {
  unsigned u = __float_as_uint(f);
  u += 0x7fffu + ((u >> 16) & 1u);  // RNE
  return (unsigned short)(u >> 16);
}

// ---------------------------------------------------------------------------
// zero fill (harness poisons d_out/d_ws with 0xAA; atomics need zeros)
// ---------------------------------------------------------------------------
__global__ void zero2(float* __restrict__ p0, int n0,
                      float* __restrict__ p1, int n1) {
  int t4 = (blockIdx.x * 256 + threadIdx.x) * 4;
  if (t4 < n0) {
    *(float4*)(p0 + t4) = float4{0.f, 0.f, 0.f, 0.f};
  } else {
    int u = t4 - n0;
    if (u < n1) *(float4*)(p1 + u) = float4{0.f, 0.f, 0.f, 0.f};
  }
}

// ---------------------------------------------------------------------------
// adjI = bf16(adj + I), 4096x4096.  1 thread = 16 contiguous elements.
// ---------------------------------------------------------------------------
__global__ void make_adjI(const float* __restrict__ adj,
                          unsigned short* __restrict__ adjb) {
  size_t t = (size_t)blockIdx.x * 256 + threadIdx.x;
  size_t base = t * 16;
  int n  = (int)(base >> 12);
  int m0 = (int)(base & 4095);
  const float4* src = (const float4*)(adj + base);
  float4 q0 = src[0], q1 = src[1], q2 = src[2], q3 = src[3];
  float vals[16] = {q0.x,q0.y,q0.z,q0.w, q1.x,q1.y,q1.z,q1.w,
                    q2.x,q2.y,q2.z,q2.w, q3.x,q3.y,q3.z,q3.w};
  ushort8 o0, o1;
#pragma unroll
  for (int j = 0; j < 8; j++) {
    float f = vals[j];     if (m0 + j == n)     f += 1.0f;
    o0[j] = f2bf(f);
  }
#pragma unroll
  for (int j = 0; j < 8; j++) {
    float f = vals[8 + j]; if (m0 + 8 + j == n) f += 1.0f;
    o1[j] = f2bf(f);
  }
  ushort8* dst = (ushort8*)(adjb + base);
  dst[0] = o0; dst[1] = o1;
}

// ---------------------------------------------------------------------------
// layer 0 linear: h = leaky_relu(x @ W), x is (b,n,d) fp32 (coalesced 64B/lane)
// writes hT bf16 [c][n], c = b*16+e.
// ---------------------------------------------------------------------------
__global__ void linear_pack(const float* __restrict__ in,
                            const float* __restrict__ W,
                            unsigned short* __restrict__ hb) {
  int tid  = threadIdx.x;
  int lane = tid & 63;
  int bq   = tid >> 6;
  int n = blockIdx.x * 64 + lane;
  int b = blockIdx.y * 4 + bq;
  size_t off = ((size_t)b * 4096 + n) * 16;
  const float4* src = (const float4*)(in + off);
  float4 q0 = src[0], q1 = src[1], q2 = src[2], q3 = src[3];
  float xr[16] = {q0.x,q0.y,q0.z,q0.w, q1.x,q1.y,q1.z,q1.w,
                  q2.x,q2.y,q2.z,q2.w, q3.x,q3.y,q3.z,q3.w};
#pragma unroll
  for (int e = 0; e < 16; e++) {
    float acc = 0.f;
#pragma unroll
    for (int d = 0; d < 16; d++) acc += xr[d] * W[d * 16 + e];
    acc = acc > 0.f ? acc : 0.2f * acc;
    hb[(size_t)(b * 16 + e) * 4096 + n] = f2bf(acc);
  }
}

// ---------------------------------------------------------------------------
// layers 1,2 linear: in = ows [n][1024] fp32.  LDS-staged so global reads are
// coalesced (r2's version read lanes 4KB apart).  Block = 16 nodes.
// LDS row stride 1025 floats -> 2-way-max bank aliasing (free).
// ---------------------------------------------------------------------------
__global__ void linear_pack_t(const float* __restrict__ in,
                              const float* __restrict__ W,
                              unsigned short* __restrict__ hb) {
  __shared__ float xs[16 * 1025];
  int n0 = blockIdx.x * 16;
  for (int i = threadIdx.x; i < 16384; i += 256) {
    int r = i >> 10, col = i & 1023;
    xs[r * 1025 + col] = in[(size_t)n0 * 1024 + i];
  }
  __syncthreads();
  int n_l = threadIdx.x & 15;
  int bq  = threadIdx.x >> 4;               // 0..15
#pragma unroll
  for (int u = 0; u < 4; ++u) {
    int b = u * 16 + bq;
    const float* xr = xs + n_l * 1025 + b * 16;
    float xv[16];
#pragma unroll
    for (int d = 0; d < 16; ++d) xv[d] = xr[d];
    float acc[16];
#pragma unroll
    for (int e = 0; e < 16; ++e) acc[e] = 0.f;
#pragma unroll
    for (int d = 0; d < 16; ++d)
#pragma unroll
      for (int e = 0; e < 16; ++e) acc[e] += xv[d] * W[d * 16 + e];
#pragma unroll
    for (int e = 0; e < 16; ++e) {
      float a = acc[e] > 0.f ? acc[e] : 0.2f * acc[e];
      hb[(size_t)(b * 16 + e) * 4096 + n0 + n_l] = f2bf(a);
    }
  }
}

// ---------------------------------------------------------------------------
// out[n][c] += adjI[n0..][kq] * hT[c0..][kq]   (one K-quarter per block)
// grid 1024 = 32 mt x 8 ct x 4 ks.  xcd = mt&7 so all ks-partials of a
// (mt,ct) accumulate in ONE XCD's L2.  Tile 128x128, BK=64, single LDS
// buffer (32 KB -> 4 blocks/CU by LDS), 4 waves, wave tile 64x64.
// XOR swizzle: phys 16B chunk = logical ^ (row&7)  [r2-verified, 0 conflicts]
// ---------------------------------------------------------------------------
__global__ __launch_bounds__(256, 3)
void gemm_ks(const unsigned short* __restrict__ A,
             const unsigned short* __restrict__ Bm,
             float* __restrict__ out, int final_mode) {
  const int K = 4096;
  __shared__ __bf16 a_s[128 * 64];   // 16 KB
  __shared__ __bf16 b_s[128 * 64];   // 16 KB

  int tid = threadIdx.x, wave = tid >> 6, lane = tid & 63;

  int lin = blockIdx.x;
  int xcd = lin & 7, g = lin >> 3;
  int mth = g & 3, ct = (g >> 2) & 7, ks = g >> 5;
  int mt = mth * 8 + xcd;            // xcd = mt&7: ks-group stays on one XCD
  int n0 = mt * 128, c0 = ct * 128;
  int kbase = ks * 1024;

  // staging: wave w covers rows w*32..w*32+31 of A and of B (4 insts each)
  int l8 = lane >> 3, lc = lane & 7;
  int swc = lc ^ l8;                 // logical chunk fetched into phys lc
  const unsigned short* gA[4];
  const unsigned short* gB[4];
#pragma unroll
  for (int j = 0; j < 4; ++j) {
    int r = wave * 32 + j * 8 + l8;
    gA[j] = A  + (size_t)(n0 + r) * K + kbase + swc * 8;
    gB[j] = Bm + (size_t)(c0 + r) * K + kbase + swc * 8;
  }

  int i16 = lane & 15, q = lane >> 4;
  int wm = wave >> 1, wn = wave & 1;
  int sw7 = i16 & 7;

  f32x4 acc[4][4] = {};

  for (int it = 0; it < 16; ++it) {
    int k0 = it * 64;
    __syncthreads();                 // prev reads done before overwrite
#pragma unroll
    for (int j = 0; j < 4; ++j) {
      GLOAD_LDS16(gA[j] + k0, a_s + (wave * 32 + j * 8) * 64);
      GLOAD_LDS16(gB[j] + k0, b_s + (wave * 32 + j * 8) * 64);
    }
    __syncthreads();                 // drains staging -> visible
#pragma unroll
    for (int s = 0; s < 2; ++s) {
      int pc = (s * 4 + q) ^ sw7;
      bf16x8 bf[4];
#pragma unroll
      for (int u = 0; u < 4; ++u)
        bf[u] = *(const bf16x8*)(b_s + (wn * 64 + u * 16 + i16) * 64 + pc * 8);
#pragma unroll
      for (int t = 0; t < 4; ++t) {
        bf16x8 af = *(const bf16x8*)(a_s + (wm * 64 + t * 16 + i16) * 64 + pc * 8);
#pragma unroll
        for (int u = 0; u < 4; ++u)
          acc[t][u] = __builtin_amdgcn_mfma_f32_16x16x32_bf16(af, bf[u], acc[t][u], 0, 0, 0);
      }
    }
  }

  // epilogue: fp32 atomic accumulate of the K-quarter partial
#pragma unroll
  for (int t = 0; t < 4; ++t)
#pragma unroll
    for (int u = 0; u < 4; ++u)
#pragma unroll
      for (int i = 0; i < 4; ++i) {
        int n_g = n0 + wm * 64 + t * 16 + q * 4 + i;
        int c_g = c0 + wn * 64 + u * 16 + i16;
        float v = acc[t][u][i];
        size_t off = final_mode
            ? ((size_t)(c_g >> 4) * 65536 + (size_t)n_g * 16 + (c_g & 15))
            : ((size_t)n_g * 1024 + c_g);
        unsafeAtomicAdd(out + off, v);
      }
}

// ---------------------------------------------------------------------------
extern "C" void kernel_launch(void* const* d_in, const int* in_sizes, int n_in,
                              void* d_out, int out_size, void* d_ws, size_t ws_size,
                              hipStream_t stream) {
  const float* x   = (const float*)d_in[0];
  const float* adj = (const float*)d_in[1];
  // d_in[2] = Identity (folded analytically)
  const float* W0  = (const float*)d_in[3];
  const float* W1  = (const float*)d_in[4];
  const float* W2  = (const float*)d_in[5];
  float* out = (float*)d_out;

  char* ws = (char*)d_ws;
  unsigned short* adjb = (unsigned short*)ws;                 // 32 MiB
  unsigned short* hb   = (unsigned short*)(ws + 33554432);    //  8 MiB
  float*          ows  = (float*)(ws + 33554432 + 8388608);   // 16 MiB

  const int NF = 4194304;  // 4M floats in ows and in d_out

  zero2<<<8192, 256, 0, stream>>>(ows, NF, out, NF);
  make_adjI<<<4096, 256, 0, stream>>>(adj, adjb);

  // layer 0
  linear_pack<<<dim3(64, 16), 256, 0, stream>>>(x, W0, hb);
  gemm_ks<<<1024, 256, 0, stream>>>(adjb, hb, ows, 0);
  // layer 1
  linear_pack_t<<<256, 256, 0, stream>>>(ows, W1, hb);
  zero2<<<4096, 256, 0, stream>>>(ows, NF, ows, 0);
  gemm_ks<<<1024, 256, 0, stream>>>(adjb, hb, ows, 0);
  // layer 2
  linear_pack_t<<<256, 256, 0, stream>>>(ows, W2, hb);
  gemm_ks<<<1024, 256, 0, stream>>>(adjb, hb, out, 1);
}

// Round 4
// 319.255 us; speedup vs baseline: 1.3485x; 1.3485x over previous
//
#include <hip/hip_runtime.h>
#include <stdint.h>

// ---------------------------------------------------------------------------
// GCN block: 3 x [ h = leaky_relu(in @ W);  out = (adj + I) @ h ]
// B=64, N=4096, D=16.  GEMM M=4096 x C=1024 x K=4096 bf16 MFMA, fp32 accum.
// Round 4: K-split-2, NO atomics (r3's 16.7M L2 atomics were the wall:
// WRITE_SIZE 16->64MB, dur flat).  Each ks-half plain-stores a bf16 partial
// (p0/p1); the p0+p1 add is fused into the next layer's linear (free) or a
// tiny coalesced add kernel for the final output.  Grid 512 = 2 blocks/CU,
// tile 128x128x64, XOR-swizzled LDS (0 conflicts, r2-verified), mt-pinned XCD.
// Workspace: adjb 32MB | hb 8MB | p0 8MB | p1 8MB  = 56MB (same as r3)
// ---------------------------------------------------------------------------

typedef __bf16 bf16x8 __attribute__((ext_vector_type(8)));
typedef float  f32x4  __attribute__((ext_vector_type(4)));
typedef unsigned short ushort8 __attribute__((ext_vector_type(8)));

typedef __attribute__((address_space(1))) void* as1p;
typedef __attribute__((address_space(3))) void* as3p;
#define GLOAD_LDS16(G, L) \
  __builtin_amdgcn_global_load_lds((as1p)(G), (as3p)(L), 16, 0, 0)

#define P_ELEMS 4194304  // elems per partial buffer (4096*1024)

__device__ __forceinline__ unsigned short f2bf(float f) {
  unsigned u = __float_as_uint(f);
  u += 0x7fffu + ((u >> 16) & 1u);  // RNE
  return (unsigned short)(u >> 16);
}
__device__ __forceinline__ float bf2f(unsigned short u) {
  return __uint_as_float(((unsigned)u) << 16);
}

// ---------------------------------------------------------------------------
// adjI = bf16(adj + I), 4096x4096.  1 thread = 16 contiguous elements.
// ---------------------------------------------------------------------------
__global__ void make_adjI(const float* __restrict__ adj,
                          unsigned short* __restrict__ adjb) {
  size_t t = (size_t)blockIdx.x * 256 + threadIdx.x;
  size_t base = t * 16;
  int n  = (int)(base >> 12);
  int m0 = (int)(base & 4095);
  const float4* src = (const float4*)(adj + base);
  float4 q0 = src[0], q1 = src[1], q2 = src[2], q3 = src[3];
  float vals[16] = {q0.x,q0.y,q0.z,q0.w, q1.x,q1.y,q1.z,q1.w,
                    q2.x,q2.y,q2.z,q2.w, q3.x,q3.y,q3.z,q3.w};
  ushort8 o0, o1;
#pragma unroll
  for (int j = 0; j < 8; j++) {
    float f = vals[j];     if (m0 + j == n)     f += 1.0f;
    o0[j] = f2bf(f);
  }
#pragma unroll
  for (int j = 0; j < 8; j++) {
    float f = vals[8 + j]; if (m0 + 8 + j == n) f += 1.0f;
    o1[j] = f2bf(f);
  }
  ushort8* dst = (ushort8*)(adjb + base);
  dst[0] = o0; dst[1] = o1;
}

// ---------------------------------------------------------------------------
// layer 0 linear: h = leaky_relu(x @ W), x (b,n,d) fp32 -> hT bf16 [c][n].
// ---------------------------------------------------------------------------
__global__ void linear_pack(const float* __restrict__ in,
                            const float* __restrict__ W,
                            unsigned short* __restrict__ hb) {
  int tid  = threadIdx.x;
  int lane = tid & 63;
  int bq   = tid >> 6;
  int n = blockIdx.x * 64 + lane;
  int b = blockIdx.y * 4 + bq;
  size_t off = ((size_t)b * 4096 + n) * 16;
  const float4* src = (const float4*)(in + off);
  float4 q0 = src[0], q1 = src[1], q2 = src[2], q3 = src[3];
  float xr[16] = {q0.x,q0.y,q0.z,q0.w, q1.x,q1.y,q1.z,q1.w,
                  q2.x,q2.y,q2.z,q2.w, q3.x,q3.y,q3.z,q3.w};
#pragma unroll
  for (int e = 0; e < 16; e++) {
    float acc = 0.f;
#pragma unroll
    for (int d = 0; d < 16; d++) acc += xr[d] * W[d * 16 + e];
    acc = acc > 0.f ? acc : 0.2f * acc;
    hb[(size_t)(b * 16 + e) * 4096 + n] = f2bf(acc);
  }
}

// ---------------------------------------------------------------------------
// layers 1,2 linear, with the k-split partial add FUSED in:
// in = p0/p1 bf16 [n][1024]; x[n][c] = p0 + p1; h = leaky_relu(x @ W);
// writes hT bf16 [c][n].  LDS-staged for coalescing; stride 1025 (no conflicts)
// ---------------------------------------------------------------------------
__global__ void linear_pack_t2(const unsigned short* __restrict__ p,
                               const float* __restrict__ W,
                               unsigned short* __restrict__ hb) {
  __shared__ float xs[16 * 1025];
  int n0 = blockIdx.x * 16;
  for (int i = threadIdx.x; i < 2048; i += 256) {   // 16384 elems / 8
    int e = i * 8;
    ushort8 a = *(const ushort8*)(p + (size_t)n0 * 1024 + e);
    ushort8 b = *(const ushort8*)(p + P_ELEMS + (size_t)n0 * 1024 + e);
    int r = e >> 10, col = e & 1023;
    float* dst = xs + r * 1025 + col;
#pragma unroll
    for (int j = 0; j < 8; ++j) dst[j] = bf2f(a[j]) + bf2f(b[j]);
  }
  __syncthreads();
  int n_l = threadIdx.x & 15;
  int bq  = threadIdx.x >> 4;               // 0..15
#pragma unroll
  for (int u = 0; u < 4; ++u) {
    int b = u * 16 + bq;
    const float* xr = xs + n_l * 1025 + b * 16;
    float xv[16];
#pragma unroll
    for (int d = 0; d < 16; ++d) xv[d] = xr[d];
    float acc[16];
#pragma unroll
    for (int e = 0; e < 16; ++e) acc[e] = 0.f;
#pragma unroll
    for (int d = 0; d < 16; ++d)
#pragma unroll
      for (int e = 0; e < 16; ++e) acc[e] += xv[d] * W[d * 16 + e];
#pragma unroll
    for (int e = 0; e < 16; ++e) {
      float a = acc[e] > 0.f ? acc[e] : 0.2f * acc[e];
      hb[(size_t)(b * 16 + e) * 4096 + n0 + n_l] = f2bf(a);
    }
  }
}

// ---------------------------------------------------------------------------
// final: out fp32 (b,n,d) = p0 + p1 (both already in (b,n,d) bf16 layout)
// ---------------------------------------------------------------------------
__global__ void add_out(const unsigned short* __restrict__ p,
                        float* __restrict__ out) {
  int i8 = (blockIdx.x * 256 + threadIdx.x) * 8;
  ushort8 a = *(const ushort8*)(p + i8);
  ushort8 b = *(const ushort8*)(p + P_ELEMS + i8);
  float4 o0, o1;
  o0.x = bf2f(a[0]) + bf2f(b[0]);  o0.y = bf2f(a[1]) + bf2f(b[1]);
  o0.z = bf2f(a[2]) + bf2f(b[2]);  o0.w = bf2f(a[3]) + bf2f(b[3]);
  o1.x = bf2f(a[4]) + bf2f(b[4]);  o1.y = bf2f(a[5]) + bf2f(b[5]);
  o1.z = bf2f(a[6]) + bf2f(b[6]);  o1.w = bf2f(a[7]) + bf2f(b[7]);
  *(float4*)(out + i8)     = o0;
  *(float4*)(out + i8 + 4) = o1;
}

// ---------------------------------------------------------------------------
// partial[n][c] (ks half of K) = adjI[n0..][k] * hT[c0..][k], plain bf16 store
// grid 512 = 32 mt x 8 ct x 2 ks, xcd = mt&7 (A slices L2-pinned).
// Tile 128x128, BK=64, single LDS buffer 32 KB, 4 waves, wave tile 64x64.
// XOR swizzle: phys 16B chunk = logical ^ (row&7)  [0 conflicts, verified]
// final_mode=0: partial layout [n][c].  final_mode=1: (b,n,d) layout.
// ---------------------------------------------------------------------------
__global__ __launch_bounds__(256, 2)
void gemm_ks2(const unsigned short* __restrict__ A,
              const unsigned short* __restrict__ Bm,
              unsigned short* __restrict__ outp, int final_mode) {
  const int K = 4096;
  __shared__ __bf16 a_s[128 * 64];   // 16 KB
  __shared__ __bf16 b_s[128 * 64];   // 16 KB

  int tid = threadIdx.x, wave = tid >> 6, lane = tid & 63;

  int lin = blockIdx.x;
  int xcd = lin & 7, g = lin >> 3;
  int mth = g & 3, ct = (g >> 2) & 7, ks = g >> 5;   // ks in {0,1}
  int mt = mth * 8 + xcd;
  int n0 = mt * 128, c0 = ct * 128;
  int kbase = ks * 2048;

  // staging: wave w covers rows w*32..w*32+31 of A and of B (4 insts each)
  int l8 = lane >> 3, lc = lane & 7;
  int swc = lc ^ l8;                 // logical chunk fetched into phys lc
  const unsigned short* gA[4];
  const unsigned short* gB[4];
#pragma unroll
  for (int j = 0; j < 4; ++j) {
    int r = wave * 32 + j * 8 + l8;
    gA[j] = A  + (size_t)(n0 + r) * K + kbase + swc * 8;
    gB[j] = Bm + (size_t)(c0 + r) * K + kbase + swc * 8;
  }

  int i16 = lane & 15, q = lane >> 4;
  int wm = wave >> 1, wn = wave & 1;
  int sw7 = i16 & 7;

  f32x4 acc[4][4] = {};

  for (int it = 0; it < 32; ++it) {
    int k0 = it * 64;
    __syncthreads();                 // prev reads done before overwrite
#pragma unroll
    for (int j = 0; j < 4; ++j) {
      GLOAD_LDS16(gA[j] + k0, a_s + (wave * 32 + j * 8) * 64);
      GLOAD_LDS16(gB[j] + k0, b_s + (wave * 32 + j * 8) * 64);
    }
    __syncthreads();                 // drains staging -> visible
#pragma unroll
    for (int s = 0; s < 2; ++s) {
      int pc = (s * 4 + q) ^ sw7;
      bf16x8 bf[4];
#pragma unroll
      for (int u = 0; u < 4; ++u)
        bf[u] = *(const bf16x8*)(b_s + (wn * 64 + u * 16 + i16) * 64 + pc * 8);
#pragma unroll
      for (int t = 0; t < 4; ++t) {
        bf16x8 af = *(const bf16x8*)(a_s + (wm * 64 + t * 16 + i16) * 64 + pc * 8);
#pragma unroll
        for (int u = 0; u < 4; ++u)
          acc[t][u] = __builtin_amdgcn_mfma_f32_16x16x32_bf16(af, bf[u], acc[t][u], 0, 0, 0);
      }
    }
  }

  // epilogue: plain bf16 stores of this K-half's partial into p[ks]
  unsigned short* dst = outp + (size_t)ks * P_ELEMS;
#pragma unroll
  for (int t = 0; t < 4; ++t)
#pragma unroll
    for (int u = 0; u < 4; ++u)
#pragma unroll
      for (int i = 0; i < 4; ++i) {
        int n_g = n0 + wm * 64 + t * 16 + q * 4 + i;
        int c_g = c0 + wn * 64 + u * 16 + i16;
        size_t off = final_mode
            ? ((size_t)(c_g >> 4) * 65536 + (size_t)n_g * 16 + (c_g & 15))
            : ((size_t)n_g * 1024 + c_g);
        dst[off] = f2bf(acc[t][u][i]);
      }
}

// ---------------------------------------------------------------------------
extern "C" void kernel_launch(void* const* d_in, const int* in_sizes, int n_in,
                              void* d_out, int out_size, void* d_ws, size_t ws_size,
                              hipStream_t stream) {
  const float* x   = (const float*)d_in[0];
  const float* adj = (const float*)d_in[1];
  // d_in[2] = Identity (folded analytically)
  const float* W0  = (const float*)d_in[3];
  const float* W1  = (const float*)d_in[4];
  const float* W2  = (const float*)d_in[5];
  float* out = (float*)d_out;

  char* ws = (char*)d_ws;
  unsigned short* adjb = (unsigned short*)ws;                 // 32 MiB
  unsigned short* hb   = (unsigned short*)(ws + 33554432);    //  8 MiB
  unsigned short* pp   = (unsigned short*)(ws + 41943040);    // p0|p1, 16 MiB

  make_adjI<<<4096, 256, 0, stream>>>(adj, adjb);

  // layer 0
  linear_pack<<<dim3(64, 16), 256, 0, stream>>>(x, W0, hb);
  gemm_ks2<<<512, 256, 0, stream>>>(adjb, hb, pp, 0);
  // layer 1
  linear_pack_t2<<<256, 256, 0, stream>>>(pp, W1, hb);
  gemm_ks2<<<512, 256, 0, stream>>>(adjb, hb, pp, 0);
  // layer 2
  linear_pack_t2<<<256, 256, 0, stream>>>(pp, W2, hb);
  gemm_ks2<<<512, 256, 0, stream>>>(adjb, hb, pp, 1);
  add_out<<<2048, 256, 0, stream>>>(pp, out);
}